// Round 3
// baseline (363.086 us; speedup 1.0000x reference)
//
#include <hip/hip_runtime.h>
#include <math.h>

constexpr int BB = 2;
constexpr int SS = 2048;
constexpr int DM = 1024;
constexpr int NH = 16;
constexpr int KD = 64;
constexpr int OUT_ELEMS  = BB*SS*DM;     // 4194304 fp32 (output 0 region)
constexpr int PRES_HALF  = BB*NH*SS*KD;  // 4194304 fp32 (k or v)
#define NEGSENT (-1e30f)

typedef __attribute__((ext_vector_type(8))) short short8;   // 8 x bf16 bits
typedef __attribute__((ext_vector_type(4))) short short4v;  // 4 x bf16 bits
typedef __attribute__((ext_vector_type(4))) float f32x4;

__device__ __forceinline__ float us2f(unsigned short u) {
  union { unsigned int ui; float f; } c; c.ui = ((unsigned int)u) << 16; return c.f;
}
__device__ __forceinline__ short f2s(float f) {
  // round-to-nearest-even bf16 (finite inputs only)
  union { float f; unsigned int u; } c; c.f = f;
  return (short)((c.u + 0x7FFFu + ((c.u >> 16) & 1u)) >> 16);
}

#define GLOAD_LDS16(g, l) \
  __builtin_amdgcn_global_load_lds((const __attribute__((address_space(1))) void*)(g), \
                                   (__attribute__((address_space(3))) void*)(l), 16, 0, 0)

// ---------------- prep: cast x[4096,1024] fp32 -> bf16 ----------------------
__global__ __launch_bounds__(256)
void cast_x_k(const float* __restrict__ x, short* __restrict__ xb) {
  const size_t i = ((size_t)blockIdx.x * 256 + threadIdx.x) * 4;
  const float4 v = *(const float4*)(x + i);
  short4v s; s.x = f2s(v.x); s.y = f2s(v.y); s.z = f2s(v.z); s.w = f2s(v.w);
  *(short4v*)(xb + i) = s;
}

// ---------------- prep: transpose w[1024,N] fp32 -> wT[N,1024] bf16 ---------
__global__ __launch_bounds__(256)
void transpose_k(const float* __restrict__ w, int N, short* __restrict__ wt) {
  __shared__ float tl[32][33];
  const int tx = threadIdx.x & 31, ty = threadIdx.x >> 5;   // 32 x 8
  const int n0 = blockIdx.x * 32, k0 = blockIdx.y * 32;
  #pragma unroll
  for (int i = 0; i < 4; ++i) {
    const int kk = ty + i * 8;
    tl[kk][tx] = w[(size_t)(k0 + kk) * N + n0 + tx];
  }
  __syncthreads();
  #pragma unroll
  for (int i = 0; i < 4; ++i) {
    const int nn = ty + i * 8;
    wt[(size_t)(n0 + nn) * 1024 + k0 + tx] = f2s(tl[tx][nn]);
  }
}

// ---------------- MFMA GEMM core (m97 structure) ----------------------------
__device__ __forceinline__ void mfma_tile_loop(
    const short* __restrict__ A, const short* __restrict__ Bt,
    int m0, int n0, short* Asm, short* Bsm, f32x4 (*acc)[4]) {
  const int tid = threadIdx.x;
  const int lane = tid & 63;
  const int w = tid >> 6;
  const int wm = (w >> 1) * 64, wn = (w & 1) * 64;
  const int ln15 = lane & 15, quad = lane >> 4;
  for (int k0 = 0; k0 < 1024; k0 += 32) {
    #pragma unroll
    for (int j = 0; j < 2; ++j) {
      const int e = j * 256 + tid;          // 0..511
      const int r = e >> 2, cq = e & 3;     // row, 16B-chunk
      GLOAD_LDS16(A  + (size_t)(m0 + r) * 1024 + k0 + cq * 8, Asm + e * 8);
      GLOAD_LDS16(Bt + (size_t)(n0 + r) * 1024 + k0 + cq * 8, Bsm + e * 8);
    }
    __syncthreads();                        // drains vmcnt before barrier
    short8 af[4], bf[4];
    #pragma unroll
    for (int t = 0; t < 4; ++t)
      af[t] = *(const short8*)(Asm + (wm + t * 16 + ln15) * 32 + quad * 8);
    #pragma unroll
    for (int t = 0; t < 4; ++t)
      bf[t] = *(const short8*)(Bsm + (wn + t * 16 + ln15) * 32 + quad * 8);
    #pragma unroll
    for (int tm = 0; tm < 4; ++tm)
      #pragma unroll
      for (int tn = 0; tn < 4; ++tn)
        acc[tm][tn] = __builtin_amdgcn_mfma_f32_16x16x32_bf16(
            af[tm], bf[tn], acc[tm][tn], 0, 0, 0);
    __syncthreads();
  }
}

// ---------------- QKV GEMM: routes v,q,k = split(qkv) ----------------------
//   n in [0,1024)    -> v fp32 -> outf[8M..12M) = present[1]; + bf16 V^T
//   n in [1024,2048) -> q bf16 -> qbf [B,H,S,KD]
//   n in [2048,3072) -> k fp32 -> outf[4M..8M)  = present[0]; + bf16 K
__global__ __launch_bounds__(256)
void qkv_mfma_k(const short* __restrict__ A, const short* __restrict__ Bt,
                const float* __restrict__ bias, short* __restrict__ qbf,
                float* __restrict__ outf, short* __restrict__ kbf,
                short* __restrict__ vbft) {
  __shared__ short Asm[128 * 32];
  __shared__ short Bsm[128 * 32];
  const int n0 = blockIdx.x * 128, m0 = blockIdx.y * 128;
  f32x4 acc[4][4] = {};
  mfma_tile_loop(A, Bt, m0, n0, Asm, Bsm, acc);
  const int lane = threadIdx.x & 63;
  const int w = threadIdx.x >> 6;
  const int wm = (w >> 1) * 64, wn = (w & 1) * 64;
  const int col = lane & 15, row4 = (lane >> 4) * 4;
  #pragma unroll
  for (int tm = 0; tm < 4; ++tm) {
    #pragma unroll
    for (int tn = 0; tn < 4; ++tn) {
      const int n = n0 + wn + tn * 16 + col;
      #pragma unroll
      for (int r = 0; r < 4; ++r) {
        const int m = m0 + wm + tm * 16 + row4 + r;
        const float val = acc[tm][tn][r] + bias[n];
        const int bb = m >> 11, s = m & 2047;
        const int c = n & 1023, h = c >> 6, d = c & 63;
        const size_t idx = ((size_t)(bb * NH + h) * SS + s) * KD + d;
        if (n < DM) {
          outf[(size_t)OUT_ELEMS + (size_t)PRES_HALF + idx] = val;   // v fp32
          if (kbf) vbft[((size_t)(bb * NH + h) * KD + d) * SS + s] = f2s(val);
        } else if (n < 2 * DM) {
          qbf[idx] = f2s(val);                                        // q bf16
        } else {
          outf[(size_t)OUT_ELEMS + idx] = val;                        // k fp32
          if (kbf) kbf[idx] = f2s(val);
        }
      }
    }
  }
}

// ---------------- Output projection: o @ w_projT + b -> out0 fp32 -----------
__global__ __launch_bounds__(256)
void proj_mfma_k(const short* __restrict__ A, const short* __restrict__ Bt,
                 const float* __restrict__ bias, float* __restrict__ outf) {
  __shared__ short Asm[128 * 32];
  __shared__ short Bsm[128 * 32];
  const int n0 = blockIdx.x * 128, m0 = blockIdx.y * 128;
  f32x4 acc[4][4] = {};
  mfma_tile_loop(A, Bt, m0, n0, Asm, Bsm, acc);
  const int lane = threadIdx.x & 63;
  const int w = threadIdx.x >> 6;
  const int wm = (w >> 1) * 64, wn = (w & 1) * 64;
  const int col = lane & 15, row4 = (lane >> 4) * 4;
  #pragma unroll
  for (int tm = 0; tm < 4; ++tm) {
    #pragma unroll
    for (int tn = 0; tn < 4; ++tn) {
      const int n = n0 + wn + tn * 16 + col;
      const float b = bias[n];
      #pragma unroll
      for (int r = 0; r < 4; ++r) {
        const int m = m0 + wm + tm * 16 + row4 + r;
        outf[(size_t)m * DM + n] = acc[tm][tn][r] + b;
      }
    }
  }
}

// ---------------- staging: one 64-key chunk of K + V^T into LDS -------------
// 128 threads; linear LDS dest (lane*16B within each wave), pre-swizzled
// global source column group (XOR row&7) so b128 fragment reads are
// conflict-free (both-sides-or-neither, rule 21).
__device__ __forceinline__ void stage_kv2(const short* __restrict__ Kg,
                                          const short* __restrict__ Vg,
                                          int kb, short* Ksb, short* Vtb,
                                          int tid) {
  #pragma unroll
  for (int rd = 0; rd < 4; ++rd) {
    const int i = rd * 128 + tid;        // 0..511 : row = i>>3, grp = i&7
    const int row = i >> 3, grp = i & 7;
    const int sw = (grp ^ (row & 7)) << 3;
    GLOAD_LDS16(Kg + (size_t)(kb + row) * KD + sw, Ksb + i * 8);
    GLOAD_LDS16(Vg + (size_t)row * SS + kb + sw, Vtb + i * 8);
  }
}

// ---------------- MFMA causal flash attention, 2-wave / double-buffered -----
// Block = (bh, y): wave 0 -> q-block p, wave 1 -> q-block 31-p where
// p = y<8 ? y : 23-y  => per-block compute constant (33 chunk-waves), K/V
// staging shared, chunk ch+1 prefetched into the alternate buffer while
// chunk ch computes (2-phase pipeline; __syncthreads drains vmcnt).
// Per-wave P round-trips through a private LDS buffer (lgkmcnt(0) fence).
__global__ __launch_bounds__(128)
void attn_mfma2_k(const short* __restrict__ qbf, const short* __restrict__ kbf,
                  const short* __restrict__ vbft, short* __restrict__ obf) {
  __shared__ short Ks[2][64 * 64];
  __shared__ short Vt[2][64 * 64];
  __shared__ short Ps[2][64 * 64];
  const int bh = blockIdx.x;                      // b*16+h
  const int by = blockIdx.y;
  const int p  = (by < 8) ? by : 23 - by;         // 0..15, heavy-first
  const int tid  = threadIdx.x;
  const int w    = tid >> 6;
  const int lane = tid & 63;
  const int qb   = w ? (31 - p) : p;
  const int q0   = qb * 64;
  const int mych = qb + 1;                        // chunks this wave computes
  const int nch  = 32 - p;                        // chunks staged (= max)
  const int ln15 = lane & 15, quad = lane >> 4;
  const int rswz = (ln15 & 7) << 3;               // fragment-read swizzle
  const float SC2 = 0.125f * 1.44269504f;         // scale * log2(e)

  // Hoist Q fragments
  short8 aq[4][2];
  {
    const short* qp = qbf + ((size_t)bh * SS + q0) * KD;
    #pragma unroll
    for (int tm = 0; tm < 4; ++tm)
      #pragma unroll
      for (int kt = 0; kt < 2; ++kt)
        aq[tm][kt] = *(const short8*)(qp + (size_t)(tm * 16 + ln15) * KD + kt * 32 + quad * 8);
  }
  f32x4 O[4][4] = {};
  float mreg[4][4], lreg[4][4];
  #pragma unroll
  for (int a = 0; a < 4; ++a)
    #pragma unroll
    for (int b = 0; b < 4; ++b) { mreg[a][b] = NEGSENT; lreg[a][b] = 0.f; }

  const short* Kg = kbf  + (size_t)bh * SS * KD;
  const short* Vg = vbft + (size_t)bh * KD * SS;
  short* Pw = Ps[w];

  stage_kv2(Kg, Vg, 0, Ks[0], Vt[0], tid);        // prologue: chunk 0 -> buf 0
  __syncthreads();

  for (int ch = 0; ch < nch; ++ch) {
    const int cur = ch & 1;
    if (ch + 1 < nch)                             // prefetch next chunk
      stage_kv2(Kg, Vg, (ch + 1) * 64, Ks[cur ^ 1], Vt[cur ^ 1], tid);

    if (ch < mych) {                              // wave-uniform branch
      const short* Kc = Ks[cur];
      const short* Vc = Vt[cur];

      // ---- QK^T ----
      f32x4 S[4][4] = {};
      #pragma unroll
      for (int kt = 0; kt < 2; ++kt) {
        short8 bk[4];
        #pragma unroll
        for (int tn = 0; tn < 4; ++tn)
          bk[tn] = *(const short8*)(Kc + (tn * 16 + ln15) * 64 + ((kt * 32 + quad * 8) ^ rswz));
        #pragma unroll
        for (int tm = 0; tm < 4; ++tm)
          #pragma unroll
          for (int tn = 0; tn < 4; ++tn)
            S[tm][tn] = __builtin_amdgcn_mfma_f32_16x16x32_bf16(aq[tm][kt], bk[tn], S[tm][tn], 0, 0, 0);
      }

      // ---- causal mask on diagonal chunk ----
      if (ch == qb) {
        #pragma unroll
        for (int tm = 0; tm < 4; ++tm) {
          const int row = tm * 16 + quad * 4;
          #pragma unroll
          for (int tn = 0; tn < 4; ++tn) {
            const int colk = tn * 16 + ln15;
            #pragma unroll
            for (int r = 0; r < 4; ++r)
              if (colk > row + r) S[tm][tn][r] = NEGSENT;
          }
        }
      }

      // ---- online softmax (exp2, scale folded) ----
      float alph[4][4];
      #pragma unroll
      for (int tm = 0; tm < 4; ++tm) {
        #pragma unroll
        for (int r = 0; r < 4; ++r) {
          float mx = fmaxf(fmaxf(S[tm][0][r], S[tm][1][r]), fmaxf(S[tm][2][r], S[tm][3][r]));
          mx = fmaxf(mx, __shfl_xor(mx, 1, 64));
          mx = fmaxf(mx, __shfl_xor(mx, 2, 64));
          mx = fmaxf(mx, __shfl_xor(mx, 4, 64));
          mx = fmaxf(mx, __shfl_xor(mx, 8, 64));
          const float mn = fmaxf(mreg[tm][r], mx);
          alph[tm][r] = exp2f((mreg[tm][r] - mn) * SC2);
          mreg[tm][r] = mn;
        }
      }
      #pragma unroll
      for (int tm = 0; tm < 4; ++tm) {
        #pragma unroll
        for (int r = 0; r < 4; ++r) {
          const float mn = mreg[tm][r], al = alph[tm][r];
          float p0 = exp2f((S[tm][0][r] - mn) * SC2);
          float p1 = exp2f((S[tm][1][r] - mn) * SC2);
          float p2 = exp2f((S[tm][2][r] - mn) * SC2);
          float p3 = exp2f((S[tm][3][r] - mn) * SC2);
          lreg[tm][r] = lreg[tm][r] * al + ((p0 + p1) + (p2 + p3));
          S[tm][0][r] = p0; S[tm][1][r] = p1; S[tm][2][r] = p2; S[tm][3][r] = p3;
          #pragma unroll
          for (int tn = 0; tn < 4; ++tn) O[tm][tn][r] *= al;
        }
      }

      // ---- P -> bf16 into private LDS, [q][k] with row-XOR swizzle ----
      #pragma unroll
      for (int tm = 0; tm < 4; ++tm) {
        const int qrow = tm * 16 + quad * 4;
        #pragma unroll
        for (int tn = 0; tn < 4; ++tn) {
          const int kc = tn * 16 + ln15;
          #pragma unroll
          for (int r = 0; r < 4; ++r)
            Pw[(qrow + r) * 64 + (kc ^ (((qrow + r) & 7) << 3))] = f2s(S[tm][tn][r]);
        }
      }
      asm volatile("s_waitcnt lgkmcnt(0)" ::: "memory");  // P visible (same wave)

      // ---- PV: O += P @ V ----
      #pragma unroll
      for (int kt = 0; kt < 2; ++kt) {
        short8 ap[4], bv[4];
        #pragma unroll
        for (int tm = 0; tm < 4; ++tm)
          ap[tm] = *(const short8*)(Pw + (tm * 16 + ln15) * 64 + ((kt * 32 + quad * 8) ^ rswz));
        #pragma unroll
        for (int tn = 0; tn < 4; ++tn)
          bv[tn] = *(const short8*)(Vc + (tn * 16 + ln15) * 64 + ((kt * 32 + quad * 8) ^ rswz));
        #pragma unroll
        for (int tm = 0; tm < 4; ++tm)
          #pragma unroll
          for (int tn = 0; tn < 4; ++tn)
            O[tm][tn] = __builtin_amdgcn_mfma_f32_16x16x32_bf16(ap[tm], bv[tn], O[tm][tn], 0, 0, 0);
      }
    }
    __syncthreads();   // drains vmcnt (next buf ready) + lgkm; all waves synced
  }

  // ---- finalize l and write o token-major ----
  #pragma unroll
  for (int tm = 0; tm < 4; ++tm)
    #pragma unroll
    for (int r = 0; r < 4; ++r) {
      float l = lreg[tm][r];
      l += __shfl_xor(l, 1, 64);
      l += __shfl_xor(l, 2, 64);
      l += __shfl_xor(l, 4, 64);
      l += __shfl_xor(l, 8, 64);
      lreg[tm][r] = 1.f / fmaxf(l, 1e-30f);
    }
  const int bb = bh >> 4, h = bh & 15;
  short* ob = obf + ((size_t)bb * SS + q0) * DM + h * KD;
  #pragma unroll
  for (int tm = 0; tm < 4; ++tm)
    #pragma unroll
    for (int tn = 0; tn < 4; ++tn)
      #pragma unroll
      for (int r = 0; r < 4; ++r)
        ob[(size_t)(tm * 16 + quad * 4 + r) * DM + tn * 16 + ln15] =
            f2s(O[tm][tn][r] * lreg[tm][r]);
}

// ---------------- legacy fp32 flash attention (fallback, small ws) ----------
__global__ __launch_bounds__(256)
void attn_k(const short* __restrict__ qbf, const float* __restrict__ pres,
            short* __restrict__ obf) {
  __shared__ float Ksf[32][64];
  __shared__ float Vsf[32][64];
  const int bh = blockIdx.x;
  const int q0 = ((int)gridDim.y - 1 - (int)blockIdx.y) * 64;
  const int t  = threadIdx.x;
  const int part = t & 3;
  const int row  = t >> 2;
  const int qr   = q0 + row;
  const int dbase = part * 16;
  const size_t qoff = ((size_t)bh * SS + qr) * KD + dbase;
  float q[16], o[16];
  #pragma unroll
  for (int i = 0; i < 16; ++i) q[i] = us2f((unsigned short)qbf[qoff + i]);
  #pragma unroll
  for (int i = 0; i < 16; ++i) o[i] = 0.f;
  float m = NEGSENT, l = 0.f;
  const float* Kb = pres + (size_t)bh * SS * KD;
  const float* Vb = pres + (size_t)PRES_HALF + (size_t)bh * SS * KD;
  const int nch = (q0 + 64) / 32;
  for (int ch = 0; ch < nch; ++ch) {
    const int kbase = ch * 32;
    __syncthreads();
    {
      const float4* ksrc = (const float4*)(Kb + (size_t)kbase * KD);
      const float4* vsrc = (const float4*)(Vb + (size_t)kbase * KD);
      float4* kdst = (float4*)&Ksf[0][0];
      float4* vdst = (float4*)&Vsf[0][0];
      #pragma unroll
      for (int i = 0; i < 2; ++i) {
        kdst[t + i * 256] = ksrc[t + i * 256];
        vdst[t + i * 256] = vsrc[t + i * 256];
      }
    }
    __syncthreads();
    float sc[32];
    #pragma unroll
    for (int kk = 0; kk < 32; ++kk) {
      float s = 0.f;
      #pragma unroll
      for (int i = 0; i < 16; ++i) s = fmaf(q[i], Ksf[kk][dbase + i], s);
      s += __shfl_xor(s, 1, 64);
      s += __shfl_xor(s, 2, 64);
      sc[kk] = (kbase + kk <= qr) ? s * 0.125f : NEGSENT;
    }
    float mc = sc[0];
    #pragma unroll
    for (int kk = 1; kk < 32; ++kk) mc = fmaxf(mc, sc[kk]);
    const float mn = fmaxf(m, mc);
    const float alpha = __expf(m - mn);
    l *= alpha;
    #pragma unroll
    for (int i = 0; i < 16; ++i) o[i] *= alpha;
    #pragma unroll
    for (int kk = 0; kk < 32; ++kk) {
      const float p = __expf(sc[kk] - mn);
      l += p;
      #pragma unroll
      for (int i = 0; i < 16; ++i) o[i] = fmaf(p, Vsf[kk][dbase + i], o[i]);
    }
    m = mn;
  }
  const float inv = 1.f / fmaxf(l, 1e-30f);
  const int bb = bh >> 4, h = bh & 15;
  const size_t ooff = ((size_t)(bb * SS + qr)) * DM + h * KD + dbase;
  #pragma unroll
  for (int i = 0; i < 16; ++i) obf[ooff + i] = f2s(o[i] * inv);
}

extern "C" void kernel_launch(void* const* d_in, const int* in_sizes, int n_in,
                              void* d_out, int out_size, void* d_ws, size_t ws_size,
                              hipStream_t stream) {
  const float* x      = (const float*)d_in[0];
  const float* w_attn = (const float*)d_in[2];
  const float* b_attn = (const float*)d_in[3];
  const float* w_proj = (const float*)d_in[4];
  const float* b_proj = (const float*)d_in[5];
  float* outf = (float*)d_out;   // fp32: [out0 4M | k 4M | v 4M] elements

  constexpr size_t MB = 1024 * 1024;
  if (ws_size >= 24 * MB) {
    // ---- MFMA-attention path ----
    // ws (shorts): [0,4M) x_bf then o_bf (lifetimes disjoint) |
    //              [4M,7M) w_attn_T | [7M,8M) w_proj_T | [8M,12M) q_bf
    // d_out out0 region (dead until proj): [0,4M) k_bf | [4M,8M) v_bfT
    short* ws0   = (short*)d_ws;
    short* x_bf  = ws0;
    short* o_bf  = ws0;
    short* wat_t = ws0 + (size_t)4 * 1024 * 1024;
    short* wpt_t = ws0 + (size_t)7 * 1024 * 1024;
    short* q_bf  = ws0 + (size_t)8 * 1024 * 1024;
    short* k_bf  = (short*)d_out;
    short* v_bft = k_bf + (size_t)PRES_HALF;

    cast_x_k<<<4096, 256, 0, stream>>>(x, x_bf);
    transpose_k<<<dim3(96, 32), 256, 0, stream>>>(w_attn, 3 * DM, wat_t);
    transpose_k<<<dim3(32, 32), 256, 0, stream>>>(w_proj, DM, wpt_t);

    qkv_mfma_k<<<dim3(24, 32), 256, 0, stream>>>(x_bf, wat_t, b_attn, q_bf, outf,
                                                 k_bf, v_bft);

    attn_mfma2_k<<<dim3(BB * NH, 16), 128, 0, stream>>>(q_bf, k_bf, v_bft, o_bf);

    proj_mfma_k<<<dim3(8, 32), 256, 0, stream>>>(o_bf, wpt_t, b_proj, outf);
  } else {
    // ---- legacy fp32-attention fallback ----
    short* x_bf;
    short* q_bf;
    short* wat_t;
    short* wpt_t;
    short* o_bf;
    if (ws_size >= 16 * MB) {
      short* ws = (short*)d_ws;
      x_bf  = (short*)d_out;                 // out0 [0,8MB) dead until proj
      q_bf  = x_bf + OUT_ELEMS;              // out0 [8MB,16MB)
      wat_t = ws;
      wpt_t = wat_t + 3 * DM * DM;
      o_bf  = wat_t + 4 * DM * DM;
    } else {
      x_bf  = (short*)d_out;
      q_bf  = x_bf + OUT_ELEMS;
      wat_t = (short*)d_in[1];
      wpt_t = wat_t + 3 * DM * DM;
      o_bf  = wat_t + 4 * DM * DM;
    }
    cast_x_k<<<4096, 256, 0, stream>>>(x, x_bf);
    transpose_k<<<dim3(96, 32), 256, 0, stream>>>(w_attn, 3 * DM, wat_t);
    transpose_k<<<dim3(32, 32), 256, 0, stream>>>(w_proj, DM, wpt_t);
    qkv_mfma_k<<<dim3(24, 32), 256, 0, stream>>>(x_bf, wat_t, b_attn, q_bf, outf,
                                                 nullptr, nullptr);
    attn_k<<<dim3(BB * NH, SS / 64), 256, 0, stream>>>(q_bf, outf + OUT_ELEMS, o_bf);
    proj_mfma_k<<<dim3(8, 32), 256, 0, stream>>>(o_bf, wpt_t, b_proj, outf);
  }
}

// Round 4
// 346.201 us; speedup vs baseline: 1.0488x; 1.0488x over previous
//
#include <hip/hip_runtime.h>
#include <math.h>

constexpr int BB = 2;
constexpr int SS = 2048;
constexpr int DM = 1024;
constexpr int NH = 16;
constexpr int KD = 64;
constexpr int OUT_ELEMS  = BB*SS*DM;     // 4194304 fp32 (output 0 region)
constexpr int PRES_HALF  = BB*NH*SS*KD;  // 4194304 fp32 (k or v)
#define NEGSENT (-1e30f)

typedef __attribute__((ext_vector_type(8))) short short8;   // 8 x bf16 bits
typedef __attribute__((ext_vector_type(4))) short short4v;  // 4 x bf16 bits
typedef __attribute__((ext_vector_type(4))) float f32x4;

__device__ __forceinline__ float us2f(unsigned short u) {
  union { unsigned int ui; float f; } c; c.ui = ((unsigned int)u) << 16; return c.f;
}
__device__ __forceinline__ short f2s(float f) {
  // round-to-nearest-even bf16 (finite inputs only)
  union { float f; unsigned int u; } c; c.f = f;
  return (short)((c.u + 0x7FFFu + ((c.u >> 16) & 1u)) >> 16);
}

#define GLOAD_LDS16(g, l) \
  __builtin_amdgcn_global_load_lds((const __attribute__((address_space(1))) void*)(g), \
                                   (__attribute__((address_space(3))) void*)(l), 16, 0, 0)

// ---------------- prep: cast x[4096,1024] fp32 -> bf16 ----------------------
__global__ __launch_bounds__(256)
void cast_x_k(const float* __restrict__ x, short* __restrict__ xb) {
  const size_t i = ((size_t)blockIdx.x * 256 + threadIdx.x) * 4;
  const float4 v = *(const float4*)(x + i);
  short4v s; s.x = f2s(v.x); s.y = f2s(v.y); s.z = f2s(v.z); s.w = f2s(v.w);
  *(short4v*)(xb + i) = s;
}

// ---------------- prep: transpose w[1024,N] fp32 -> wT[N,1024] bf16 ---------
__global__ __launch_bounds__(256)
void transpose_k(const float* __restrict__ w, int N, short* __restrict__ wt) {
  __shared__ float tl[32][33];
  const int tx = threadIdx.x & 31, ty = threadIdx.x >> 5;   // 32 x 8
  const int n0 = blockIdx.x * 32, k0 = blockIdx.y * 32;
  #pragma unroll
  for (int i = 0; i < 4; ++i) {
    const int kk = ty + i * 8;
    tl[kk][tx] = w[(size_t)(k0 + kk) * N + n0 + tx];
  }
  __syncthreads();
  #pragma unroll
  for (int i = 0; i < 4; ++i) {
    const int nn = ty + i * 8;
    wt[(size_t)(n0 + nn) * 1024 + k0 + tx] = f2s(tl[tx][nn]);
  }
}

// ---------------- MFMA GEMM core (m97 structure) ----------------------------
__device__ __forceinline__ void mfma_tile_loop(
    const short* __restrict__ A, const short* __restrict__ Bt,
    int m0, int n0, short* Asm, short* Bsm, f32x4 (*acc)[4]) {
  const int tid = threadIdx.x;
  const int lane = tid & 63;
  const int w = tid >> 6;
  const int wm = (w >> 1) * 64, wn = (w & 1) * 64;
  const int ln15 = lane & 15, quad = lane >> 4;
  for (int k0 = 0; k0 < 1024; k0 += 32) {
    #pragma unroll
    for (int j = 0; j < 2; ++j) {
      const int e = j * 256 + tid;          // 0..511
      const int r = e >> 2, cq = e & 3;     // row, 16B-chunk
      GLOAD_LDS16(A  + (size_t)(m0 + r) * 1024 + k0 + cq * 8, Asm + e * 8);
      GLOAD_LDS16(Bt + (size_t)(n0 + r) * 1024 + k0 + cq * 8, Bsm + e * 8);
    }
    __syncthreads();                        // drains vmcnt before barrier
    short8 af[4], bf[4];
    #pragma unroll
    for (int t = 0; t < 4; ++t)
      af[t] = *(const short8*)(Asm + (wm + t * 16 + ln15) * 32 + quad * 8);
    #pragma unroll
    for (int t = 0; t < 4; ++t)
      bf[t] = *(const short8*)(Bsm + (wn + t * 16 + ln15) * 32 + quad * 8);
    #pragma unroll
    for (int tm = 0; tm < 4; ++tm)
      #pragma unroll
      for (int tn = 0; tn < 4; ++tn)
        acc[tm][tn] = __builtin_amdgcn_mfma_f32_16x16x32_bf16(
            af[tm], bf[tn], acc[tm][tn], 0, 0, 0);
    __syncthreads();
  }
}

// ---------------- QKV GEMM: routes v,q,k = split(qkv) ----------------------
//   n in [0,1024)    -> v fp32 -> outf[8M..12M) = present[1]; + bf16 V^T
//   n in [1024,2048) -> q bf16 -> qbf [B,H,S,KD]
//   n in [2048,3072) -> k fp32 -> outf[4M..8M)  = present[0]; + bf16 K
__global__ __launch_bounds__(256)
void qkv_mfma_k(const short* __restrict__ A, const short* __restrict__ Bt,
                const float* __restrict__ bias, short* __restrict__ qbf,
                float* __restrict__ outf, short* __restrict__ kbf,
                short* __restrict__ vbft) {
  __shared__ short Asm[128 * 32];
  __shared__ short Bsm[128 * 32];
  const int n0 = blockIdx.x * 128, m0 = blockIdx.y * 128;
  f32x4 acc[4][4] = {};
  mfma_tile_loop(A, Bt, m0, n0, Asm, Bsm, acc);
  const int lane = threadIdx.x & 63;
  const int w = threadIdx.x >> 6;
  const int wm = (w >> 1) * 64, wn = (w & 1) * 64;
  const int col = lane & 15, row4 = (lane >> 4) * 4;
  #pragma unroll
  for (int tm = 0; tm < 4; ++tm) {
    #pragma unroll
    for (int tn = 0; tn < 4; ++tn) {
      const int n = n0 + wn + tn * 16 + col;
      #pragma unroll
      for (int r = 0; r < 4; ++r) {
        const int m = m0 + wm + tm * 16 + row4 + r;
        const float val = acc[tm][tn][r] + bias[n];
        const int bb = m >> 11, s = m & 2047;
        const int c = n & 1023, h = c >> 6, d = c & 63;
        const size_t idx = ((size_t)(bb * NH + h) * SS + s) * KD + d;
        if (n < DM) {
          outf[(size_t)OUT_ELEMS + (size_t)PRES_HALF + idx] = val;   // v fp32
          if (kbf) vbft[((size_t)(bb * NH + h) * KD + d) * SS + s] = f2s(val);
        } else if (n < 2 * DM) {
          qbf[idx] = f2s(val);                                        // q bf16
        } else {
          outf[(size_t)OUT_ELEMS + idx] = val;                        // k fp32
          if (kbf) kbf[idx] = f2s(val);
        }
      }
    }
  }
}

// ---------------- Output projection: o @ w_projT + b -> out0 fp32 -----------
__global__ __launch_bounds__(256)
void proj_mfma_k(const short* __restrict__ A, const short* __restrict__ Bt,
                 const float* __restrict__ bias, float* __restrict__ outf) {
  __shared__ short Asm[128 * 32];
  __shared__ short Bsm[128 * 32];
  const int n0 = blockIdx.x * 128, m0 = blockIdx.y * 128;
  f32x4 acc[4][4] = {};
  mfma_tile_loop(A, Bt, m0, n0, Asm, Bsm, acc);
  const int lane = threadIdx.x & 63;
  const int w = threadIdx.x >> 6;
  const int wm = (w >> 1) * 64, wn = (w & 1) * 64;
  const int col = lane & 15, row4 = (lane >> 4) * 4;
  #pragma unroll
  for (int tm = 0; tm < 4; ++tm) {
    #pragma unroll
    for (int tn = 0; tn < 4; ++tn) {
      const int n = n0 + wn + tn * 16 + col;
      const float b = bias[n];
      #pragma unroll
      for (int r = 0; r < 4; ++r) {
        const int m = m0 + wm + tm * 16 + row4 + r;
        outf[(size_t)m * DM + n] = acc[tm][tn][r] + b;
      }
    }
  }
}

// ---------------- staging: one 64-key chunk of K + V^T into LDS (1 wave) ----
// 16 global_load_lds (8 K + 8 V). Linear LDS dest (lane*16B), pre-swizzled
// global source (XOR row&7 on the 16B column group) so the b128 fragment
// reads are bank-conflict-free (both-sides-or-neither, rule 21).
__device__ __forceinline__ void stage_kv1(const short* __restrict__ Kg,
                                          const short* __restrict__ Vg,
                                          int kb, short* Ksb, short* Vtb,
                                          int lane) {
  const int sub = lane >> 3, grp = lane & 7;
  #pragma unroll
  for (int g = 0; g < 8; ++g) {
    const int row = g * 8 + sub;
    const int sw = (grp ^ (row & 7)) << 3;
    GLOAD_LDS16(Kg + (size_t)(kb + row) * KD + sw, Ksb + g * 512 + lane * 8);
    GLOAD_LDS16(Vg + (size_t)row * SS + kb + sw, Vtb + g * 512 + lane * 8);
  }
}

// ---------------- MFMA causal flash attention, 1-wave + wave-local dbuf -----
// Block = 1 wave owning 64 q rows of one (b,h); 64-key chunks double-buffered:
// chunk ch+1's 16 global_load_lds are issued BEFORE computing chunk ch, then
// s_waitcnt vmcnt(16) (counted, never 0 mid-loop) -- staging latency hides
// under compute. No __syncthreads anywhere (single wave). P reuses the dead
// current K buffer (LDS 32 KB). O-rescale sits between P-write and the lgkm
// fence to fill the wait. blockIdx.y reversed: longest causal blocks first.
__global__ __launch_bounds__(64)
void attn_mfma3_k(const short* __restrict__ qbf, const short* __restrict__ kbf,
                  const short* __restrict__ vbft, short* __restrict__ obf) {
  __shared__ short Ks[2][64 * 64];
  __shared__ short Vt[2][64 * 64];
  const int bh = blockIdx.x;                      // b*16+h (same bh -> same XCD)
  const int qb = 31 - (int)blockIdx.y;            // longest-first
  const int q0 = qb * 64;
  const int lane = threadIdx.x;
  const int ln15 = lane & 15, quad = lane >> 4;
  const int rswz = (ln15 & 7) << 3;               // fragment-read swizzle (shorts)
  const float SC2 = 0.125f * 1.44269504f;         // scale * log2(e)

  // Hoist Q fragments: aq[tm][kt] = Q[q0+tm*16+ln15][kt*32+quad*8 ..+7]
  short8 aq[4][2];
  {
    const short* qp = qbf + ((size_t)bh * SS + q0) * KD;
    #pragma unroll
    for (int tm = 0; tm < 4; ++tm)
      #pragma unroll
      for (int kt = 0; kt < 2; ++kt)
        aq[tm][kt] = *(const short8*)(qp + (size_t)(tm * 16 + ln15) * KD + kt * 32 + quad * 8);
  }
  f32x4 O[4][4] = {};
  float mreg[4][4], lreg[4][4];
  #pragma unroll
  for (int a = 0; a < 4; ++a)
    #pragma unroll
    for (int b = 0; b < 4; ++b) { mreg[a][b] = NEGSENT; lreg[a][b] = 0.f; }

  const short* Kg = kbf  + (size_t)bh * SS * KD;
  const short* Vg = vbft + (size_t)bh * KD * SS;
  const int nch = qb + 1;

  stage_kv1(Kg, Vg, 0, Ks[0], Vt[0], lane);       // prologue: chunk 0 -> buf 0

  for (int ch = 0; ch < nch; ++ch) {
    const int cur = ch & 1;
    short* Kc = Ks[cur];
    const short* Vc = Vt[cur];
    if (ch + 1 < nch) {                           // prefetch next chunk
      stage_kv1(Kg, Vg, (ch + 1) * 64, Ks[cur ^ 1], Vt[cur ^ 1], lane);
      asm volatile("s_waitcnt vmcnt(16)" ::: "memory");  // cur-buf loads done
    } else {
      asm volatile("s_waitcnt vmcnt(0)" ::: "memory");
    }
    __builtin_amdgcn_sched_barrier(0);            // rule 18: pin reads after wait

    // ---- QK^T: S[q 64][k 64] ----
    f32x4 S[4][4] = {};
    #pragma unroll
    for (int kt = 0; kt < 2; ++kt) {
      short8 bk[4];
      #pragma unroll
      for (int tn = 0; tn < 4; ++tn)
        bk[tn] = *(const short8*)(Kc + (tn * 16 + ln15) * 64 + ((kt * 32 + quad * 8) ^ rswz));
      #pragma unroll
      for (int tm = 0; tm < 4; ++tm)
        #pragma unroll
        for (int tn = 0; tn < 4; ++tn)
          S[tm][tn] = __builtin_amdgcn_mfma_f32_16x16x32_bf16(aq[tm][kt], bk[tn], S[tm][tn], 0, 0, 0);
    }

    // ---- causal mask on the diagonal chunk ----
    if (ch == qb) {
      #pragma unroll
      for (int tm = 0; tm < 4; ++tm) {
        const int row = tm * 16 + quad * 4;
        #pragma unroll
        for (int tn = 0; tn < 4; ++tn) {
          const int colk = tn * 16 + ln15;
          #pragma unroll
          for (int r = 0; r < 4; ++r)
            if (colk > row + r) S[tm][tn][r] = NEGSENT;
        }
      }
    }

    // ---- online softmax (exp2, scale folded) ----
    float alph[4][4];
    #pragma unroll
    for (int tm = 0; tm < 4; ++tm) {
      #pragma unroll
      for (int r = 0; r < 4; ++r) {
        float mx = fmaxf(fmaxf(S[tm][0][r], S[tm][1][r]), fmaxf(S[tm][2][r], S[tm][3][r]));
        mx = fmaxf(mx, __shfl_xor(mx, 1, 64));
        mx = fmaxf(mx, __shfl_xor(mx, 2, 64));
        mx = fmaxf(mx, __shfl_xor(mx, 4, 64));
        mx = fmaxf(mx, __shfl_xor(mx, 8, 64));
        const float mn = fmaxf(mreg[tm][r], mx);
        alph[tm][r] = exp2f((mreg[tm][r] - mn) * SC2);
        mreg[tm][r] = mn;
      }
    }
    // ---- P = exp(S - m), accumulate l, write P -> Kc (K dead), swizzled ----
    #pragma unroll
    for (int tm = 0; tm < 4; ++tm) {
      const int qrow = tm * 16 + quad * 4;
      #pragma unroll
      for (int r = 0; r < 4; ++r) {
        const float mn = mreg[tm][r], al = alph[tm][r];
        float p0 = exp2f((S[tm][0][r] - mn) * SC2);
        float p1 = exp2f((S[tm][1][r] - mn) * SC2);
        float p2 = exp2f((S[tm][2][r] - mn) * SC2);
        float p3 = exp2f((S[tm][3][r] - mn) * SC2);
        lreg[tm][r] = lreg[tm][r] * al + ((p0 + p1) + (p2 + p3));
        const int rs = ((qrow + r) & 7) << 3;
        Kc[(qrow + r) * 64 + ((0 * 16 + ln15) ^ rs)] = f2s(p0);
        Kc[(qrow + r) * 64 + ((1 * 16 + ln15) ^ rs)] = f2s(p1);
        Kc[(qrow + r) * 64 + ((2 * 16 + ln15) ^ rs)] = f2s(p2);
        Kc[(qrow + r) * 64 + ((3 * 16 + ln15) ^ rs)] = f2s(p3);
      }
    }
    // ---- O-rescale fills the lgkm shadow ----
    #pragma unroll
    for (int tm = 0; tm < 4; ++tm)
      #pragma unroll
      for (int r = 0; r < 4; ++r) {
        const float al = alph[tm][r];
        #pragma unroll
        for (int tn = 0; tn < 4; ++tn) O[tm][tn][r] *= al;
      }
    asm volatile("s_waitcnt lgkmcnt(0)" ::: "memory");  // P writes landed
    __builtin_amdgcn_sched_barrier(0);                   // rule 18

    // ---- PV: O += P @ V ----
    #pragma unroll
    for (int kt = 0; kt < 2; ++kt) {
      short8 ap[4], bv[4];
      #pragma unroll
      for (int tm = 0; tm < 4; ++tm)
        ap[tm] = *(const short8*)(Kc + (tm * 16 + ln15) * 64 + ((kt * 32 + quad * 8) ^ rswz));
      #pragma unroll
      for (int tn = 0; tn < 4; ++tn)
        bv[tn] = *(const short8*)(Vc + (tn * 16 + ln15) * 64 + ((kt * 32 + quad * 8) ^ rswz));
      #pragma unroll
      for (int tm = 0; tm < 4; ++tm)
        #pragma unroll
        for (int tn = 0; tn < 4; ++tn)
          O[tm][tn] = __builtin_amdgcn_mfma_f32_16x16x32_bf16(ap[tm], bv[tn], O[tm][tn], 0, 0, 0);
    }
  }

  // ---- finalize l (deferred cross-lane reduce) and write o token-major ----
  #pragma unroll
  for (int tm = 0; tm < 4; ++tm)
    #pragma unroll
    for (int r = 0; r < 4; ++r) {
      float l = lreg[tm][r];
      l += __shfl_xor(l, 1, 64);
      l += __shfl_xor(l, 2, 64);
      l += __shfl_xor(l, 4, 64);
      l += __shfl_xor(l, 8, 64);
      lreg[tm][r] = 1.f / fmaxf(l, 1e-30f);
    }
  const int bb = bh >> 4, h = bh & 15;
  short* ob = obf + ((size_t)bb * SS + q0) * DM + h * KD;
  #pragma unroll
  for (int tm = 0; tm < 4; ++tm)
    #pragma unroll
    for (int tn = 0; tn < 4; ++tn)
      #pragma unroll
      for (int r = 0; r < 4; ++r)
        ob[(size_t)(tm * 16 + quad * 4 + r) * DM + tn * 16 + ln15] =
            f2s(O[tm][tn][r] * lreg[tm][r]);
}

// ---------------- legacy fp32 flash attention (fallback, small ws) ----------
__global__ __launch_bounds__(256)
void attn_k(const short* __restrict__ qbf, const float* __restrict__ pres,
            short* __restrict__ obf) {
  __shared__ float Ksf[32][64];
  __shared__ float Vsf[32][64];
  const int bh = blockIdx.x;
  const int q0 = ((int)gridDim.y - 1 - (int)blockIdx.y) * 64;
  const int t  = threadIdx.x;
  const int part = t & 3;
  const int row  = t >> 2;
  const int qr   = q0 + row;
  const int dbase = part * 16;
  const size_t qoff = ((size_t)bh * SS + qr) * KD + dbase;
  float q[16], o[16];
  #pragma unroll
  for (int i = 0; i < 16; ++i) q[i] = us2f((unsigned short)qbf[qoff + i]);
  #pragma unroll
  for (int i = 0; i < 16; ++i) o[i] = 0.f;
  float m = NEGSENT, l = 0.f;
  const float* Kb = pres + (size_t)bh * SS * KD;
  const float* Vb = pres + (size_t)PRES_HALF + (size_t)bh * SS * KD;
  const int nch = (q0 + 64) / 32;
  for (int ch = 0; ch < nch; ++ch) {
    const int kbase = ch * 32;
    __syncthreads();
    {
      const float4* ksrc = (const float4*)(Kb + (size_t)kbase * KD);
      const float4* vsrc = (const float4*)(Vb + (size_t)kbase * KD);
      float4* kdst = (float4*)&Ksf[0][0];
      float4* vdst = (float4*)&Vsf[0][0];
      #pragma unroll
      for (int i = 0; i < 2; ++i) {
        kdst[t + i * 256] = ksrc[t + i * 256];
        vdst[t + i * 256] = vsrc[t + i * 256];
      }
    }
    __syncthreads();
    float sc[32];
    #pragma unroll
    for (int kk = 0; kk < 32; ++kk) {
      float s = 0.f;
      #pragma unroll
      for (int i = 0; i < 16; ++i) s = fmaf(q[i], Ksf[kk][dbase + i], s);
      s += __shfl_xor(s, 1, 64);
      s += __shfl_xor(s, 2, 64);
      sc[kk] = (kbase + kk <= qr) ? s * 0.125f : NEGSENT;
    }
    float mc = sc[0];
    #pragma unroll
    for (int kk = 1; kk < 32; ++kk) mc = fmaxf(mc, sc[kk]);
    const float mn = fmaxf(m, mc);
    const float alpha = __expf(m - mn);
    l *= alpha;
    #pragma unroll
    for (int i = 0; i < 16; ++i) o[i] *= alpha;
    #pragma unroll
    for (int kk = 0; kk < 32; ++kk) {
      const float p = __expf(sc[kk] - mn);
      l += p;
      #pragma unroll
      for (int i = 0; i < 16; ++i) o[i] = fmaf(p, Vsf[kk][dbase + i], o[i]);
    }
    m = mn;
  }
  const float inv = 1.f / fmaxf(l, 1e-30f);
  const int bb = bh >> 4, h = bh & 15;
  const size_t ooff = ((size_t)(bb * SS + qr)) * DM + h * KD + dbase;
  #pragma unroll
  for (int i = 0; i < 16; ++i) obf[ooff + i] = f2s(o[i] * inv);
}

extern "C" void kernel_launch(void* const* d_in, const int* in_sizes, int n_in,
                              void* d_out, int out_size, void* d_ws, size_t ws_size,
                              hipStream_t stream) {
  const float* x      = (const float*)d_in[0];
  const float* w_attn = (const float*)d_in[2];
  const float* b_attn = (const float*)d_in[3];
  const float* w_proj = (const float*)d_in[4];
  const float* b_proj = (const float*)d_in[5];
  float* outf = (float*)d_out;   // fp32: [out0 4M | k 4M | v 4M] elements

  constexpr size_t MB = 1024 * 1024;
  if (ws_size >= 24 * MB) {
    // ---- MFMA-attention path ----
    // ws (shorts): [0,4M) x_bf then o_bf (lifetimes disjoint) |
    //              [4M,7M) w_attn_T | [7M,8M) w_proj_T | [8M,12M) q_bf
    // d_out out0 region (dead until proj): [0,4M) k_bf | [4M,8M) v_bfT
    short* ws0   = (short*)d_ws;
    short* x_bf  = ws0;
    short* o_bf  = ws0;
    short* wat_t = ws0 + (size_t)4 * 1024 * 1024;
    short* wpt_t = ws0 + (size_t)7 * 1024 * 1024;
    short* q_bf  = ws0 + (size_t)8 * 1024 * 1024;
    short* k_bf  = (short*)d_out;
    short* v_bft = k_bf + (size_t)PRES_HALF;

    cast_x_k<<<4096, 256, 0, stream>>>(x, x_bf);
    transpose_k<<<dim3(96, 32), 256, 0, stream>>>(w_attn, 3 * DM, wat_t);
    transpose_k<<<dim3(32, 32), 256, 0, stream>>>(w_proj, DM, wpt_t);

    qkv_mfma_k<<<dim3(24, 32), 256, 0, stream>>>(x_bf, wat_t, b_attn, q_bf, outf,
                                                 k_bf, v_bft);

    attn_mfma3_k<<<dim3(BB * NH, SS / 64), 64, 0, stream>>>(q_bf, k_bf, v_bft, o_bf);

    proj_mfma_k<<<dim3(8, 32), 256, 0, stream>>>(o_bf, wpt_t, b_proj, outf);
  } else {
    // ---- legacy fp32-attention fallback ----
    short* x_bf;
    short* q_bf;
    short* wat_t;
    short* wpt_t;
    short* o_bf;
    if (ws_size >= 16 * MB) {
      short* ws = (short*)d_ws;
      x_bf  = (short*)d_out;                 // out0 [0,8MB) dead until proj
      q_bf  = x_bf + OUT_ELEMS;              // out0 [8MB,16MB)
      wat_t = ws;
      wpt_t = wat_t + 3 * DM * DM;
      o_bf  = wat_t + 4 * DM * DM;
    } else {
      x_bf  = (short*)d_out;
      q_bf  = x_bf + OUT_ELEMS;
      wat_t = (short*)d_in[1];
      wpt_t = wat_t + 3 * DM * DM;
      o_bf  = wat_t + 4 * DM * DM;
    }
    cast_x_k<<<4096, 256, 0, stream>>>(x, x_bf);
    transpose_k<<<dim3(96, 32), 256, 0, stream>>>(w_attn, 3 * DM, wat_t);
    transpose_k<<<dim3(32, 32), 256, 0, stream>>>(w_proj, DM, wpt_t);
    qkv_mfma_k<<<dim3(24, 32), 256, 0, stream>>>(x_bf, wat_t, b_attn, q_bf, outf,
                                                 nullptr, nullptr);
    attn_k<<<dim3(BB * NH, SS / 64), 256, 0, stream>>>(q_bf, outf + OUT_ELEMS, o_bf);
    proj_mfma_k<<<dim3(8, 32), 256, 0, stream>>>(o_bf, wpt_t, b_proj, outf);
  }
}

// Round 5
// 247.480 us; speedup vs baseline: 1.4671x; 1.3989x over previous
//
#include <hip/hip_runtime.h>
#include <math.h>

constexpr int BB = 2;
constexpr int SS = 2048;
constexpr int DM = 1024;
constexpr int NH = 16;
constexpr int KD = 64;
constexpr int OUT_ELEMS  = BB*SS*DM;     // 4194304 fp32 (output 0 region)
constexpr int PRES_HALF  = BB*NH*SS*KD;  // 4194304 fp32 (k or v)
#define NEGSENT (-1e30f)

typedef __attribute__((ext_vector_type(8))) short short8;   // 8 x bf16 bits
typedef __attribute__((ext_vector_type(4))) short short4v;  // 4 x bf16 bits
typedef __attribute__((ext_vector_type(4))) float f32x4;

__device__ __forceinline__ float us2f(unsigned short u) {
  union { unsigned int ui; float f; } c; c.ui = ((unsigned int)u) << 16; return c.f;
}
__device__ __forceinline__ short f2s(float f) {
  // round-to-nearest-even bf16 (finite inputs only)
  union { float f; unsigned int u; } c; c.f = f;
  return (short)((c.u + 0x7FFFu + ((c.u >> 16) & 1u)) >> 16);
}

#define GLOAD_LDS16(g, l) \
  __builtin_amdgcn_global_load_lds((const __attribute__((address_space(1))) void*)(g), \
                                   (__attribute__((address_space(3))) void*)(l), 16, 0, 0)

// ---------------- prep: cast x[4096,1024] fp32 -> bf16 ----------------------
__global__ __launch_bounds__(256)
void cast_x_k(const float* __restrict__ x, short* __restrict__ xb) {
  const size_t i = ((size_t)blockIdx.x * 256 + threadIdx.x) * 4;
  const float4 v = *(const float4*)(x + i);
  short4v s; s.x = f2s(v.x); s.y = f2s(v.y); s.z = f2s(v.z); s.w = f2s(v.w);
  *(short4v*)(xb + i) = s;
}

// ---------------- prep: transpose w[1024,N] fp32 -> wT[N,1024] bf16 ---------
__global__ __launch_bounds__(256)
void transpose_k(const float* __restrict__ w, int N, short* __restrict__ wt) {
  __shared__ float tl[32][33];
  const int tx = threadIdx.x & 31, ty = threadIdx.x >> 5;   // 32 x 8
  const int n0 = blockIdx.x * 32, k0 = blockIdx.y * 32;
  #pragma unroll
  for (int i = 0; i < 4; ++i) {
    const int kk = ty + i * 8;
    tl[kk][tx] = w[(size_t)(k0 + kk) * N + n0 + tx];
  }
  __syncthreads();
  #pragma unroll
  for (int i = 0; i < 4; ++i) {
    const int nn = ty + i * 8;
    wt[(size_t)(n0 + nn) * 1024 + k0 + tx] = f2s(tl[tx][nn]);
  }
}

// ---------------- MFMA GEMM core (m97 structure) ----------------------------
__device__ __forceinline__ void mfma_tile_loop(
    const short* __restrict__ A, const short* __restrict__ Bt,
    int m0, int n0, short* Asm, short* Bsm, f32x4 (*acc)[4]) {
  const int tid = threadIdx.x;
  const int lane = tid & 63;
  const int w = tid >> 6;
  const int wm = (w >> 1) * 64, wn = (w & 1) * 64;
  const int ln15 = lane & 15, quad = lane >> 4;
  for (int k0 = 0; k0 < 1024; k0 += 32) {
    #pragma unroll
    for (int j = 0; j < 2; ++j) {
      const int e = j * 256 + tid;          // 0..511
      const int r = e >> 2, cq = e & 3;     // row, 16B-chunk
      GLOAD_LDS16(A  + (size_t)(m0 + r) * 1024 + k0 + cq * 8, Asm + e * 8);
      GLOAD_LDS16(Bt + (size_t)(n0 + r) * 1024 + k0 + cq * 8, Bsm + e * 8);
    }
    __syncthreads();                        // drains vmcnt before barrier
    short8 af[4], bf[4];
    #pragma unroll
    for (int t = 0; t < 4; ++t)
      af[t] = *(const short8*)(Asm + (wm + t * 16 + ln15) * 32 + quad * 8);
    #pragma unroll
    for (int t = 0; t < 4; ++t)
      bf[t] = *(const short8*)(Bsm + (wn + t * 16 + ln15) * 32 + quad * 8);
    #pragma unroll
    for (int tm = 0; tm < 4; ++tm)
      #pragma unroll
      for (int tn = 0; tn < 4; ++tn)
        acc[tm][tn] = __builtin_amdgcn_mfma_f32_16x16x32_bf16(
            af[tm], bf[tn], acc[tm][tn], 0, 0, 0);
    __syncthreads();
  }
}

// ---------------- QKV GEMM: routes v,q,k = split(qkv) ----------------------
//   n in [0,1024)    -> v fp32 -> outf[8M..12M) = present[1]; + bf16 V^T
//   n in [1024,2048) -> q bf16 -> qbf [B,H,S,KD]
//   n in [2048,3072) -> k fp32 -> outf[4M..8M)  = present[0]; + bf16 K
__global__ __launch_bounds__(256)
void qkv_mfma_k(const short* __restrict__ A, const short* __restrict__ Bt,
                const float* __restrict__ bias, short* __restrict__ qbf,
                float* __restrict__ outf, short* __restrict__ kbf,
                short* __restrict__ vbft) {
  __shared__ short Asm[128 * 32];
  __shared__ short Bsm[128 * 32];
  const int n0 = blockIdx.x * 128, m0 = blockIdx.y * 128;
  f32x4 acc[4][4] = {};
  mfma_tile_loop(A, Bt, m0, n0, Asm, Bsm, acc);
  const int lane = threadIdx.x & 63;
  const int w = threadIdx.x >> 6;
  const int wm = (w >> 1) * 64, wn = (w & 1) * 64;
  const int col = lane & 15, row4 = (lane >> 4) * 4;
  #pragma unroll
  for (int tm = 0; tm < 4; ++tm) {
    #pragma unroll
    for (int tn = 0; tn < 4; ++tn) {
      const int n = n0 + wn + tn * 16 + col;
      #pragma unroll
      for (int r = 0; r < 4; ++r) {
        const int m = m0 + wm + tm * 16 + row4 + r;
        const float val = acc[tm][tn][r] + bias[n];
        const int bb = m >> 11, s = m & 2047;
        const int c = n & 1023, h = c >> 6, d = c & 63;
        const size_t idx = ((size_t)(bb * NH + h) * SS + s) * KD + d;
        if (n < DM) {
          outf[(size_t)OUT_ELEMS + (size_t)PRES_HALF + idx] = val;   // v fp32
          if (kbf) vbft[((size_t)(bb * NH + h) * KD + d) * SS + s] = f2s(val);
        } else if (n < 2 * DM) {
          qbf[idx] = f2s(val);                                        // q bf16
        } else {
          outf[(size_t)OUT_ELEMS + idx] = val;                        // k fp32
          if (kbf) kbf[idx] = f2s(val);
        }
      }
    }
  }
}

// ---------------- Output projection: o @ w_projT + b -> out0 fp32 -----------
__global__ __launch_bounds__(256)
void proj_mfma_k(const short* __restrict__ A, const short* __restrict__ Bt,
                 const float* __restrict__ bias, float* __restrict__ outf) {
  __shared__ short Asm[128 * 32];
  __shared__ short Bsm[128 * 32];
  const int n0 = blockIdx.x * 128, m0 = blockIdx.y * 128;
  f32x4 acc[4][4] = {};
  mfma_tile_loop(A, Bt, m0, n0, Asm, Bsm, acc);
  const int lane = threadIdx.x & 63;
  const int w = threadIdx.x >> 6;
  const int wm = (w >> 1) * 64, wn = (w & 1) * 64;
  const int col = lane & 15, row4 = (lane >> 4) * 4;
  #pragma unroll
  for (int tm = 0; tm < 4; ++tm) {
    #pragma unroll
    for (int tn = 0; tn < 4; ++tn) {
      const int n = n0 + wn + tn * 16 + col;
      const float b = bias[n];
      #pragma unroll
      for (int r = 0; r < 4; ++r) {
        const int m = m0 + wm + tm * 16 + row4 + r;
        outf[(size_t)m * DM + n] = acc[tm][tn][r] + b;
      }
    }
  }
}

// ---------------- staging: one 64-key chunk of K + V^T, 256 threads ---------
// 2 K-loads + 2 V-loads per thread. Linear LDS dest (wave-uniform base +
// lane*16B), pre-swizzled global source (XOR row&7 on the 16B column group)
// so b128 fragment reads are conflict-free (both-sides-or-neither, rule 21).
__device__ __forceinline__ void stage_kv4(const short* __restrict__ Kg,
                                          const short* __restrict__ Vg,
                                          int kb, short* Ksb, short* Vtb,
                                          int tid) {
  #pragma unroll
  for (int rd = 0; rd < 2; ++rd) {
    const int i = rd * 256 + tid;        // 0..511 : row = i>>3, grp = i&7
    const int row = i >> 3, grp = i & 7;
    const int sw = (grp ^ (row & 7)) << 3;
    GLOAD_LDS16(Kg + (size_t)(kb + row) * KD + sw, Ksb + i * 8);
    GLOAD_LDS16(Vg + (size_t)row * SS + kb + sw, Vtb + i * 8);
  }
}

// ---------------- MFMA causal flash attention, 4-wave shared staging --------
// Block = 256 thr = 4 waves, owns 64 q rows of one (b,h); wave w computes
// rows w*16..w*16+15 (M=16). K[64][64] and V^T[64][64] staged ONCE per chunk
// by all 4 waves; simple 2-barrier structure -- latency hidden by cross-block
// wave overlap (24 KB LDS, ~4 blocks/CU = 16 waves/CU vs 2 before).
// XCD-bijective grid remap: xcd = bid&7 serves only 4 heads -> K/V+Q ~3 MB
// fits the 4 MB per-XCD L2 (kills the 12.4 GB L2-miss overfetch).
__global__ __launch_bounds__(256)
void attn_mfma4_k(const short* __restrict__ qbf, const short* __restrict__ kbf,
                  const short* __restrict__ vbft, short* __restrict__ obf) {
  __shared__ short Ks[64 * 64];       // K chunk  [key][d], swizzled
  __shared__ short Vt[64 * 64];       // V^T chunk [d][key], swizzled
  __shared__ short Ps[4][16 * 64];    // per-wave P [qrow][key], swizzled
  const int bid = blockIdx.x;
  const int xcd = bid & 7, g = bid >> 3;
  const int bh  = (xcd << 2) | (g >> 5);          // 4 heads per XCD
  const int qb  = 31 - (g & 31);                  // longest-first per head
  const int q0  = qb * 64;
  const int tid = threadIdx.x;
  const int w   = tid >> 6;
  const int lane = tid & 63;
  const int ln15 = lane & 15, quad = lane >> 4;
  const int rswz = (ln15 & 7) << 3;               // fragment-read swizzle
  const float SC2 = 0.125f * 1.44269504f;         // scale * log2(e)

  // Q fragments for this wave's 16 rows: row = ln15, k = kt*32 + quad*8
  short8 aq[2];
  {
    const short* qp = qbf + ((size_t)bh * SS + q0 + w * 16) * KD;
    aq[0] = *(const short8*)(qp + (size_t)ln15 * KD + quad * 8);
    aq[1] = *(const short8*)(qp + (size_t)ln15 * KD + 32 + quad * 8);
  }
  f32x4 O[4] = {};                    // [tn], rows quad*4+r
  float mreg[4], lreg[4];             // [r]
  #pragma unroll
  for (int r = 0; r < 4; ++r) { mreg[r] = NEGSENT; lreg[r] = 0.f; }

  const short* Kg = kbf  + (size_t)bh * SS * KD;
  const short* Vg = vbft + (size_t)bh * KD * SS;
  short* Pw = Ps[w];
  const int nch = qb + 1;

  for (int ch = 0; ch < nch; ++ch) {
    __syncthreads();                  // all waves done reading prev K/V tile
    stage_kv4(Kg, Vg, ch * 64, Ks, Vt, tid);
    __syncthreads();                  // staging complete (vmcnt drained)

    // ---- QK^T: S[16 q][64 k] ----
    f32x4 S[4] = {};
    #pragma unroll
    for (int kt = 0; kt < 2; ++kt) {
      short8 bk[4];
      #pragma unroll
      for (int tn = 0; tn < 4; ++tn)
        bk[tn] = *(const short8*)(Ks + (tn * 16 + ln15) * 64 + ((kt * 32 + quad * 8) ^ rswz));
      #pragma unroll
      for (int tn = 0; tn < 4; ++tn)
        S[tn] = __builtin_amdgcn_mfma_f32_16x16x32_bf16(aq[kt], bk[tn], S[tn], 0, 0, 0);
    }

    // ---- causal mask on the diagonal chunk (kb == q0) ----
    if (ch == qb) {
      const int rowl = w * 16 + quad * 4;
      #pragma unroll
      for (int tn = 0; tn < 4; ++tn) {
        const int colk = tn * 16 + ln15;
        #pragma unroll
        for (int r = 0; r < 4; ++r)
          if (colk > rowl + r) S[tn][r] = NEGSENT;
      }
    }

    // ---- online softmax (exp2, scale folded); rows = quad*4+r ----
    float alph[4];
    #pragma unroll
    for (int r = 0; r < 4; ++r) {
      float mx = fmaxf(fmaxf(S[0][r], S[1][r]), fmaxf(S[2][r], S[3][r]));
      mx = fmaxf(mx, __shfl_xor(mx, 1, 64));
      mx = fmaxf(mx, __shfl_xor(mx, 2, 64));
      mx = fmaxf(mx, __shfl_xor(mx, 4, 64));
      mx = fmaxf(mx, __shfl_xor(mx, 8, 64));
      const float mn = fmaxf(mreg[r], mx);
      alph[r] = exp2f((mreg[r] - mn) * SC2);
      mreg[r] = mn;
    }
    #pragma unroll
    for (int r = 0; r < 4; ++r) {
      const float mn = mreg[r], al = alph[r];
      const int prow = quad * 4 + r;
      const int rs = (prow & 7) << 3;
      float p0 = exp2f((S[0][r] - mn) * SC2);
      float p1 = exp2f((S[1][r] - mn) * SC2);
      float p2 = exp2f((S[2][r] - mn) * SC2);
      float p3 = exp2f((S[3][r] - mn) * SC2);
      lreg[r] = lreg[r] * al + ((p0 + p1) + (p2 + p3));
      Pw[prow * 64 + ((0 * 16 + ln15) ^ rs)] = f2s(p0);
      Pw[prow * 64 + ((1 * 16 + ln15) ^ rs)] = f2s(p1);
      Pw[prow * 64 + ((2 * 16 + ln15) ^ rs)] = f2s(p2);
      Pw[prow * 64 + ((3 * 16 + ln15) ^ rs)] = f2s(p3);
      O[0][r] *= al; O[1][r] *= al; O[2][r] *= al; O[3][r] *= al;
    }
    asm volatile("s_waitcnt lgkmcnt(0)" ::: "memory");  // own P writes landed
    __builtin_amdgcn_sched_barrier(0);                  // rule 18

    // ---- PV: O += P @ V ----
    #pragma unroll
    for (int kt = 0; kt < 2; ++kt) {
      short8 ap = *(const short8*)(Pw + ln15 * 64 + ((kt * 32 + quad * 8) ^ rswz));
      short8 bv[4];
      #pragma unroll
      for (int tn = 0; tn < 4; ++tn)
        bv[tn] = *(const short8*)(Vt + (tn * 16 + ln15) * 64 + ((kt * 32 + quad * 8) ^ rswz));
      #pragma unroll
      for (int tn = 0; tn < 4; ++tn)
        O[tn] = __builtin_amdgcn_mfma_f32_16x16x32_bf16(ap, bv[tn], O[tn], 0, 0, 0);
    }
  }

  // ---- finalize l and write o token-major ----
  #pragma unroll
  for (int r = 0; r < 4; ++r) {
    float l = lreg[r];
    l += __shfl_xor(l, 1, 64);
    l += __shfl_xor(l, 2, 64);
    l += __shfl_xor(l, 4, 64);
    l += __shfl_xor(l, 8, 64);
    lreg[r] = 1.f / fmaxf(l, 1e-30f);
  }
  const int bb = bh >> 4, h = bh & 15;
  short* ob = obf + ((size_t)bb * SS + q0 + w * 16) * DM + h * KD;
  #pragma unroll
  for (int tn = 0; tn < 4; ++tn)
    #pragma unroll
    for (int r = 0; r < 4; ++r)
      ob[(size_t)(quad * 4 + r) * DM + tn * 16 + ln15] = f2s(O[tn][r] * lreg[r]);
}

// ---------------- legacy fp32 flash attention (fallback, small ws) ----------
__global__ __launch_bounds__(256)
void attn_k(const short* __restrict__ qbf, const float* __restrict__ pres,
            short* __restrict__ obf) {
  __shared__ float Ksf[32][64];
  __shared__ float Vsf[32][64];
  const int bh = blockIdx.x;
  const int q0 = ((int)gridDim.y - 1 - (int)blockIdx.y) * 64;
  const int t  = threadIdx.x;
  const int part = t & 3;
  const int row  = t >> 2;
  const int qr   = q0 + row;
  const int dbase = part * 16;
  const size_t qoff = ((size_t)bh * SS + qr) * KD + dbase;
  float q[16], o[16];
  #pragma unroll
  for (int i = 0; i < 16; ++i) q[i] = us2f((unsigned short)qbf[qoff + i]);
  #pragma unroll
  for (int i = 0; i < 16; ++i) o[i] = 0.f;
  float m = NEGSENT, l = 0.f;
  const float* Kb = pres + (size_t)bh * SS * KD;
  const float* Vb = pres + (size_t)PRES_HALF + (size_t)bh * SS * KD;
  const int nch = (q0 + 64) / 32;
  for (int ch = 0; ch < nch; ++ch) {
    const int kbase = ch * 32;
    __syncthreads();
    {
      const float4* ksrc = (const float4*)(Kb + (size_t)kbase * KD);
      const float4* vsrc = (const float4*)(Vb + (size_t)kbase * KD);
      float4* kdst = (float4*)&Ksf[0][0];
      float4* vdst = (float4*)&Vsf[0][0];
      #pragma unroll
      for (int i = 0; i < 2; ++i) {
        kdst[t + i * 256] = ksrc[t + i * 256];
        vdst[t + i * 256] = vsrc[t + i * 256];
      }
    }
    __syncthreads();
    float sc[32];
    #pragma unroll
    for (int kk = 0; kk < 32; ++kk) {
      float s = 0.f;
      #pragma unroll
      for (int i = 0; i < 16; ++i) s = fmaf(q[i], Ksf[kk][dbase + i], s);
      s += __shfl_xor(s, 1, 64);
      s += __shfl_xor(s, 2, 64);
      sc[kk] = (kbase + kk <= qr) ? s * 0.125f : NEGSENT;
    }
    float mc = sc[0];
    #pragma unroll
    for (int kk = 1; kk < 32; ++kk) mc = fmaxf(mc, sc[kk]);
    const float mn = fmaxf(m, mc);
    const float alpha = __expf(m - mn);
    l *= alpha;
    #pragma unroll
    for (int i = 0; i < 16; ++i) o[i] *= alpha;
    #pragma unroll
    for (int kk = 0; kk < 32; ++kk) {
      const float p = __expf(sc[kk] - mn);
      l += p;
      #pragma unroll
      for (int i = 0; i < 16; ++i) o[i] = fmaf(p, Vsf[kk][dbase + i], o[i]);
    }
    m = mn;
  }
  const float inv = 1.f / fmaxf(l, 1e-30f);
  const int bb = bh >> 4, h = bh & 15;
  const size_t ooff = ((size_t)(bb * SS + qr)) * DM + h * KD + dbase;
  #pragma unroll
  for (int i = 0; i < 16; ++i) obf[ooff + i] = f2s(o[i] * inv);
}

extern "C" void kernel_launch(void* const* d_in, const int* in_sizes, int n_in,
                              void* d_out, int out_size, void* d_ws, size_t ws_size,
                              hipStream_t stream) {
  const float* x      = (const float*)d_in[0];
  const float* w_attn = (const float*)d_in[2];
  const float* b_attn = (const float*)d_in[3];
  const float* w_proj = (const float*)d_in[4];
  const float* b_proj = (const float*)d_in[5];
  float* outf = (float*)d_out;   // fp32: [out0 4M | k 4M | v 4M] elements

  constexpr size_t MB = 1024 * 1024;
  if (ws_size >= 24 * MB) {
    // ---- MFMA-attention path ----
    // ws (shorts): [0,4M) x_bf then o_bf (lifetimes disjoint) |
    //              [4M,7M) w_attn_T | [7M,8M) w_proj_T | [8M,12M) q_bf
    // d_out out0 region (dead until proj): [0,4M) k_bf | [4M,8M) v_bfT
    short* ws0   = (short*)d_ws;
    short* x_bf  = ws0;
    short* o_bf  = ws0;
    short* wat_t = ws0 + (size_t)4 * 1024 * 1024;
    short* wpt_t = ws0 + (size_t)7 * 1024 * 1024;
    short* q_bf  = ws0 + (size_t)8 * 1024 * 1024;
    short* k_bf  = (short*)d_out;
    short* v_bft = k_bf + (size_t)PRES_HALF;

    cast_x_k<<<4096, 256, 0, stream>>>(x, x_bf);
    transpose_k<<<dim3(96, 32), 256, 0, stream>>>(w_attn, 3 * DM, wat_t);
    transpose_k<<<dim3(32, 32), 256, 0, stream>>>(w_proj, DM, wpt_t);

    qkv_mfma_k<<<dim3(24, 32), 256, 0, stream>>>(x_bf, wat_t, b_attn, q_bf, outf,
                                                 k_bf, v_bft);

    attn_mfma4_k<<<dim3(BB * NH * (SS / 64)), 256, 0, stream>>>(q_bf, k_bf, v_bft, o_bf);

    proj_mfma_k<<<dim3(8, 32), 256, 0, stream>>>(o_bf, wpt_t, b_proj, outf);
  } else {
    // ---- legacy fp32-attention fallback ----
    short* x_bf;
    short* q_bf;
    short* wat_t;
    short* wpt_t;
    short* o_bf;
    if (ws_size >= 16 * MB) {
      short* ws = (short*)d_ws;
      x_bf  = (short*)d_out;                 // out0 [0,8MB) dead until proj
      q_bf  = x_bf + OUT_ELEMS;              // out0 [8MB,16MB)
      wat_t = ws;
      wpt_t = wat_t + 3 * DM * DM;
      o_bf  = wat_t + 4 * DM * DM;
    } else {
      x_bf  = (short*)d_out;
      q_bf  = x_bf + OUT_ELEMS;
      wat_t = (short*)d_in[1];
      wpt_t = wat_t + 3 * DM * DM;
      o_bf  = wat_t + 4 * DM * DM;
    }
    cast_x_k<<<4096, 256, 0, stream>>>(x, x_bf);
    transpose_k<<<dim3(96, 32), 256, 0, stream>>>(w_attn, 3 * DM, wat_t);
    transpose_k<<<dim3(32, 32), 256, 0, stream>>>(w_proj, DM, wpt_t);
    qkv_mfma_k<<<dim3(24, 32), 256, 0, stream>>>(x_bf, wat_t, b_attn, q_bf, outf,
                                                 nullptr, nullptr);
    attn_k<<<dim3(BB * NH, SS / 64), 256, 0, stream>>>(q_bf, outf + OUT_ELEMS, o_bf);
    proj_mfma_k<<<dim3(8, 32), 256, 0, stream>>>(o_bf, wpt_t, b_proj, outf);
  }
}

// Round 6
// 236.682 us; speedup vs baseline: 1.5341x; 1.0456x over previous
//
#include <hip/hip_runtime.h>
#include <math.h>

constexpr int BB = 2;
constexpr int SS = 2048;
constexpr int DM = 1024;
constexpr int NH = 16;
constexpr int KD = 64;
constexpr int OUT_ELEMS  = BB*SS*DM;     // 4194304 fp32 (output 0 region)
constexpr int PRES_HALF  = BB*NH*SS*KD;  // 4194304 fp32 (k or v)
#define NEGSENT (-1e30f)

typedef __attribute__((ext_vector_type(8))) short short8;   // 8 x bf16 bits
typedef __attribute__((ext_vector_type(4))) short short4v;  // 4 x bf16 bits
typedef __attribute__((ext_vector_type(4))) float f32x4;

__device__ __forceinline__ float us2f(unsigned short u) {
  union { unsigned int ui; float f; } c; c.ui = ((unsigned int)u) << 16; return c.f;
}
__device__ __forceinline__ short f2s(float f) {
  // round-to-nearest-even bf16 (finite inputs only)
  union { float f; unsigned int u; } c; c.f = f;
  return (short)((c.u + 0x7FFFu + ((c.u >> 16) & 1u)) >> 16);
}

#define GLOAD_LDS16(g, l) \
  __builtin_amdgcn_global_load_lds((const __attribute__((address_space(1))) void*)(g), \
                                   (__attribute__((address_space(3))) void*)(l), 16, 0, 0)

// ---------------- prep: cast x[4096,1024] fp32 -> bf16 ----------------------
__global__ __launch_bounds__(256)
void cast_x_k(const float* __restrict__ x, short* __restrict__ xb) {
  const size_t i = ((size_t)blockIdx.x * 256 + threadIdx.x) * 4;
  const float4 v = *(const float4*)(x + i);
  short4v s; s.x = f2s(v.x); s.y = f2s(v.y); s.z = f2s(v.z); s.w = f2s(v.w);
  *(short4v*)(xb + i) = s;
}

// ---------------- prep: transpose w[1024,N] fp32 -> wT[N,1024] bf16 ---------
__global__ __launch_bounds__(256)
void transpose_k(const float* __restrict__ w, int N, short* __restrict__ wt) {
  __shared__ float tl[32][33];
  const int tx = threadIdx.x & 31, ty = threadIdx.x >> 5;   // 32 x 8
  const int n0 = blockIdx.x * 32, k0 = blockIdx.y * 32;
  #pragma unroll
  for (int i = 0; i < 4; ++i) {
    const int kk = ty + i * 8;
    tl[kk][tx] = w[(size_t)(k0 + kk) * N + n0 + tx];
  }
  __syncthreads();
  #pragma unroll
  for (int i = 0; i < 4; ++i) {
    const int nn = ty + i * 8;
    wt[(size_t)(n0 + nn) * 1024 + k0 + tx] = f2s(tl[tx][nn]);
  }
}

// ---------------- MFMA GEMM core (m97 structure) ----------------------------
__device__ __forceinline__ void mfma_tile_loop(
    const short* __restrict__ A, const short* __restrict__ Bt,
    int m0, int n0, short* Asm, short* Bsm, f32x4 (*acc)[4]) {
  const int tid = threadIdx.x;
  const int lane = tid & 63;
  const int w = tid >> 6;
  const int wm = (w >> 1) * 64, wn = (w & 1) * 64;
  const int ln15 = lane & 15, quad = lane >> 4;
  for (int k0 = 0; k0 < 1024; k0 += 32) {
    #pragma unroll
    for (int j = 0; j < 2; ++j) {
      const int e = j * 256 + tid;          // 0..511
      const int r = e >> 2, cq = e & 3;     // row, 16B-chunk
      GLOAD_LDS16(A  + (size_t)(m0 + r) * 1024 + k0 + cq * 8, Asm + e * 8);
      GLOAD_LDS16(Bt + (size_t)(n0 + r) * 1024 + k0 + cq * 8, Bsm + e * 8);
    }
    __syncthreads();                        // drains vmcnt before barrier
    short8 af[4], bf[4];
    #pragma unroll
    for (int t = 0; t < 4; ++t)
      af[t] = *(const short8*)(Asm + (wm + t * 16 + ln15) * 32 + quad * 8);
    #pragma unroll
    for (int t = 0; t < 4; ++t)
      bf[t] = *(const short8*)(Bsm + (wn + t * 16 + ln15) * 32 + quad * 8);
    #pragma unroll
    for (int tm = 0; tm < 4; ++tm)
      #pragma unroll
      for (int tn = 0; tn < 4; ++tn)
        acc[tm][tn] = __builtin_amdgcn_mfma_f32_16x16x32_bf16(
            af[tm], bf[tn], acc[tm][tn], 0, 0, 0);
    __syncthreads();
  }
}

// ---------------- QKV GEMM: routes v,q,k = split(qkv) ----------------------
//   n in [0,1024)    -> v fp32 -> outf[8M..12M) = present[1]; + bf16 V^T
//   n in [1024,2048) -> q bf16 -> qbf [B,H,S,KD]
//   n in [2048,3072) -> k fp32 -> outf[4M..8M)  = present[0]; + bf16 K
__global__ __launch_bounds__(256)
void qkv_mfma_k(const short* __restrict__ A, const short* __restrict__ Bt,
                const float* __restrict__ bias, short* __restrict__ qbf,
                float* __restrict__ outf, short* __restrict__ kbf,
                short* __restrict__ vbft) {
  __shared__ short Asm[128 * 32];
  __shared__ short Bsm[128 * 32];
  const int n0 = blockIdx.x * 128, m0 = blockIdx.y * 128;
  f32x4 acc[4][4] = {};
  mfma_tile_loop(A, Bt, m0, n0, Asm, Bsm, acc);
  const int lane = threadIdx.x & 63;
  const int w = threadIdx.x >> 6;
  const int wm = (w >> 1) * 64, wn = (w & 1) * 64;
  const int col = lane & 15, row4 = (lane >> 4) * 4;
  #pragma unroll
  for (int tm = 0; tm < 4; ++tm) {
    #pragma unroll
    for (int tn = 0; tn < 4; ++tn) {
      const int n = n0 + wn + tn * 16 + col;
      #pragma unroll
      for (int r = 0; r < 4; ++r) {
        const int m = m0 + wm + tm * 16 + row4 + r;
        const float val = acc[tm][tn][r] + bias[n];
        const int bb = m >> 11, s = m & 2047;
        const int c = n & 1023, h = c >> 6, d = c & 63;
        const size_t idx = ((size_t)(bb * NH + h) * SS + s) * KD + d;
        if (n < DM) {
          outf[(size_t)OUT_ELEMS + (size_t)PRES_HALF + idx] = val;   // v fp32
          if (kbf) vbft[((size_t)(bb * NH + h) * KD + d) * SS + s] = f2s(val);
        } else if (n < 2 * DM) {
          qbf[idx] = f2s(val);                                        // q bf16
        } else {
          outf[(size_t)OUT_ELEMS + idx] = val;                        // k fp32
          if (kbf) kbf[idx] = f2s(val);
        }
      }
    }
  }
}

// ---------------- Output projection: o @ w_projT + b -> out0 fp32 -----------
__global__ __launch_bounds__(256)
void proj_mfma_k(const short* __restrict__ A, const short* __restrict__ Bt,
                 const float* __restrict__ bias, float* __restrict__ outf) {
  __shared__ short Asm[128 * 32];
  __shared__ short Bsm[128 * 32];
  const int n0 = blockIdx.x * 128, m0 = blockIdx.y * 128;
  f32x4 acc[4][4] = {};
  mfma_tile_loop(A, Bt, m0, n0, Asm, Bsm, acc);
  const int lane = threadIdx.x & 63;
  const int w = threadIdx.x >> 6;
  const int wm = (w >> 1) * 64, wn = (w & 1) * 64;
  const int col = lane & 15, row4 = (lane >> 4) * 4;
  #pragma unroll
  for (int tm = 0; tm < 4; ++tm) {
    #pragma unroll
    for (int tn = 0; tn < 4; ++tn) {
      const int n = n0 + wn + tn * 16 + col;
      const float b = bias[n];
      #pragma unroll
      for (int r = 0; r < 4; ++r) {
        const int m = m0 + wm + tm * 16 + row4 + r;
        outf[(size_t)m * DM + n] = acc[tm][tn][r] + b;
      }
    }
  }
}

// ---------------- staging: one 64-key chunk of K + V^T, 256 threads ---------
// 2 K-loads + 2 V-loads per thread. Linear LDS dest (wave-uniform base +
// lane*16B), pre-swizzled global source (XOR row&7 on the 16B column group)
// so b128 fragment reads are conflict-free (both-sides-or-neither, rule 21).
__device__ __forceinline__ void stage_kv4(const short* __restrict__ Kg,
                                          const short* __restrict__ Vg,
                                          int kb, short* Ksb, short* Vtb,
                                          int tid) {
  #pragma unroll
  for (int rd = 0; rd < 2; ++rd) {
    const int i = rd * 256 + tid;        // 0..511 : row = i>>3, grp = i&7
    const int row = i >> 3, grp = i & 7;
    const int sw = (grp ^ (row & 7)) << 3;
    GLOAD_LDS16(Kg + (size_t)(kb + row) * KD + sw, Ksb + i * 8);
    GLOAD_LDS16(Vg + (size_t)row * SS + kb + sw, Vtb + i * 8);
  }
}

// ---------------- MFMA causal flash attention, 4-wave, dbuf + balanced ------
// Block = 256 thr = 4 waves, owns 64 q rows of one (b,h); wave w computes
// rows w*16..w*16+15. K/V double-buffered: stage(ch+1) issued BEFORE
// computing ch, single __syncthreads per chunk (T3 2-phase; barrier's
// vmcnt-drain lands after a full compute phase). Grid mapping is
// XCD-bijective AND per-CU balanced: within an XCD, alternate rounds flip
// the qb order so each CU's 4 blocks total a constant 66 chunks (fixes the
// R5 imbalance where CU c got qb=31-c four times: 128 vs 4 chunk-iters).
__global__ __launch_bounds__(256)
void attn_mfma5_k(const short* __restrict__ qbf, const short* __restrict__ kbf,
                  const short* __restrict__ vbft, short* __restrict__ obf) {
  __shared__ short Ks[2][64 * 64];    // K chunk  [key][d], swizzled
  __shared__ short Vt[2][64 * 64];    // V^T chunk [d][key], swizzled
  __shared__ short Ps[4][16 * 64];    // per-wave P [qrow][key], swizzled
  const int bid = blockIdx.x;
  const int xcd = bid & 7, g = bid >> 3;
  const int rr  = g & 31, rnd = g >> 5;           // round = head index 0..3
  const int bh  = (xcd << 2) | rnd;               // 4 heads per XCD
  const int qb  = (rnd & 1) ? rr : 31 - rr;       // alternate-round flip
  const int q0  = qb * 64;
  const int tid = threadIdx.x;
  const int w   = tid >> 6;
  const int lane = tid & 63;
  const int ln15 = lane & 15, quad = lane >> 4;
  const int rswz = (ln15 & 7) << 3;               // fragment-read swizzle
  const float SC2 = 0.125f * 1.44269504f;         // scale * log2(e)

  // Q fragments for this wave's 16 rows: row = ln15, k = kt*32 + quad*8
  short8 aq[2];
  {
    const short* qp = qbf + ((size_t)bh * SS + q0 + w * 16) * KD;
    aq[0] = *(const short8*)(qp + (size_t)ln15 * KD + quad * 8);
    aq[1] = *(const short8*)(qp + (size_t)ln15 * KD + 32 + quad * 8);
  }
  f32x4 O[4] = {};                    // [tn], rows quad*4+r
  float mreg[4], lreg[4];             // [r]
  #pragma unroll
  for (int r = 0; r < 4; ++r) { mreg[r] = NEGSENT; lreg[r] = 0.f; }

  const short* Kg = kbf  + (size_t)bh * SS * KD;
  const short* Vg = vbft + (size_t)bh * KD * SS;
  short* Pw = Ps[w];
  const int nch = qb + 1;

  stage_kv4(Kg, Vg, 0, Ks[0], Vt[0], tid);   // prologue: chunk 0 -> buf 0
  __syncthreads();

  for (int ch = 0; ch < nch; ++ch) {
    const int cur = ch & 1;
    if (ch + 1 < nch)                        // issue next-chunk loads first
      stage_kv4(Kg, Vg, (ch + 1) * 64, Ks[cur ^ 1], Vt[cur ^ 1], tid);
    const short* Kc = Ks[cur];
    const short* Vc = Vt[cur];

    // ---- QK^T: S[16 q][64 k] ----
    f32x4 S[4] = {};
    #pragma unroll
    for (int kt = 0; kt < 2; ++kt) {
      short8 bk[4];
      #pragma unroll
      for (int tn = 0; tn < 4; ++tn)
        bk[tn] = *(const short8*)(Kc + (tn * 16 + ln15) * 64 + ((kt * 32 + quad * 8) ^ rswz));
      #pragma unroll
      for (int tn = 0; tn < 4; ++tn)
        S[tn] = __builtin_amdgcn_mfma_f32_16x16x32_bf16(aq[kt], bk[tn], S[tn], 0, 0, 0);
    }

    // ---- causal mask on the diagonal chunk ----
    if (ch == qb) {
      const int rowl = w * 16 + quad * 4;
      #pragma unroll
      for (int tn = 0; tn < 4; ++tn) {
        const int colk = tn * 16 + ln15;
        #pragma unroll
        for (int r = 0; r < 4; ++r)
          if (colk > rowl + r) S[tn][r] = NEGSENT;
      }
    }

    // ---- online softmax (exp2, scale folded); rows = quad*4+r ----
    float alph[4];
    #pragma unroll
    for (int r = 0; r < 4; ++r) {
      float mx = fmaxf(fmaxf(S[0][r], S[1][r]), fmaxf(S[2][r], S[3][r]));
      mx = fmaxf(mx, __shfl_xor(mx, 1, 64));
      mx = fmaxf(mx, __shfl_xor(mx, 2, 64));
      mx = fmaxf(mx, __shfl_xor(mx, 4, 64));
      mx = fmaxf(mx, __shfl_xor(mx, 8, 64));
      const float mn = fmaxf(mreg[r], mx);
      alph[r] = exp2f((mreg[r] - mn) * SC2);
      mreg[r] = mn;
    }
    #pragma unroll
    for (int r = 0; r < 4; ++r) {
      const float mn = mreg[r], al = alph[r];
      const int prow = quad * 4 + r;
      const int rs = (prow & 7) << 3;
      float p0 = exp2f((S[0][r] - mn) * SC2);
      float p1 = exp2f((S[1][r] - mn) * SC2);
      float p2 = exp2f((S[2][r] - mn) * SC2);
      float p3 = exp2f((S[3][r] - mn) * SC2);
      lreg[r] = lreg[r] * al + ((p0 + p1) + (p2 + p3));
      Pw[prow * 64 + ((0 * 16 + ln15) ^ rs)] = f2s(p0);
      Pw[prow * 64 + ((1 * 16 + ln15) ^ rs)] = f2s(p1);
      Pw[prow * 64 + ((2 * 16 + ln15) ^ rs)] = f2s(p2);
      Pw[prow * 64 + ((3 * 16 + ln15) ^ rs)] = f2s(p3);
      O[0][r] *= al; O[1][r] *= al; O[2][r] *= al; O[3][r] *= al;
    }
    asm volatile("s_waitcnt lgkmcnt(0)" ::: "memory");  // own P writes landed
    __builtin_amdgcn_sched_barrier(0);                  // rule 18

    // ---- PV: O += P @ V ----
    #pragma unroll
    for (int kt = 0; kt < 2; ++kt) {
      short8 ap = *(const short8*)(Pw + ln15 * 64 + ((kt * 32 + quad * 8) ^ rswz));
      short8 bv[4];
      #pragma unroll
      for (int tn = 0; tn < 4; ++tn)
        bv[tn] = *(const short8*)(Vc + (tn * 16 + ln15) * 64 + ((kt * 32 + quad * 8) ^ rswz));
      #pragma unroll
      for (int tn = 0; tn < 4; ++tn)
        O[tn] = __builtin_amdgcn_mfma_f32_16x16x32_bf16(ap, bv[tn], O[tn], 0, 0, 0);
    }
    __syncthreads();   // next buf staged+visible; prev reads done
  }

  // ---- finalize l and write o token-major ----
  #pragma unroll
  for (int r = 0; r < 4; ++r) {
    float l = lreg[r];
    l += __shfl_xor(l, 1, 64);
    l += __shfl_xor(l, 2, 64);
    l += __shfl_xor(l, 4, 64);
    l += __shfl_xor(l, 8, 64);
    lreg[r] = 1.f / fmaxf(l, 1e-30f);
  }
  const int bb = bh >> 4, h = bh & 15;
  short* ob = obf + ((size_t)bb * SS + q0 + w * 16) * DM + h * KD;
  #pragma unroll
  for (int tn = 0; tn < 4; ++tn)
    #pragma unroll
    for (int r = 0; r < 4; ++r)
      ob[(size_t)(quad * 4 + r) * DM + tn * 16 + ln15] = f2s(O[tn][r] * lreg[r]);
}

// ---------------- legacy fp32 flash attention (fallback, small ws) ----------
__global__ __launch_bounds__(256)
void attn_k(const short* __restrict__ qbf, const float* __restrict__ pres,
            short* __restrict__ obf) {
  __shared__ float Ksf[32][64];
  __shared__ float Vsf[32][64];
  const int bh = blockIdx.x;
  const int q0 = ((int)gridDim.y - 1 - (int)blockIdx.y) * 64;
  const int t  = threadIdx.x;
  const int part = t & 3;
  const int row  = t >> 2;
  const int qr   = q0 + row;
  const int dbase = part * 16;
  const size_t qoff = ((size_t)bh * SS + qr) * KD + dbase;
  float q[16], o[16];
  #pragma unroll
  for (int i = 0; i < 16; ++i) q[i] = us2f((unsigned short)qbf[qoff + i]);
  #pragma unroll
  for (int i = 0; i < 16; ++i) o[i] = 0.f;
  float m = NEGSENT, l = 0.f;
  const float* Kb = pres + (size_t)bh * SS * KD;
  const float* Vb = pres + (size_t)PRES_HALF + (size_t)bh * SS * KD;
  const int nch = (q0 + 64) / 32;
  for (int ch = 0; ch < nch; ++ch) {
    const int kbase = ch * 32;
    __syncthreads();
    {
      const float4* ksrc = (const float4*)(Kb + (size_t)kbase * KD);
      const float4* vsrc = (const float4*)(Vb + (size_t)kbase * KD);
      float4* kdst = (float4*)&Ksf[0][0];
      float4* vdst = (float4*)&Vsf[0][0];
      #pragma unroll
      for (int i = 0; i < 2; ++i) {
        kdst[t + i * 256] = ksrc[t + i * 256];
        vdst[t + i * 256] = vsrc[t + i * 256];
      }
    }
    __syncthreads();
    float sc[32];
    #pragma unroll
    for (int kk = 0; kk < 32; ++kk) {
      float s = 0.f;
      #pragma unroll
      for (int i = 0; i < 16; ++i) s = fmaf(q[i], Ksf[kk][dbase + i], s);
      s += __shfl_xor(s, 1, 64);
      s += __shfl_xor(s, 2, 64);
      sc[kk] = (kbase + kk <= qr) ? s * 0.125f : NEGSENT;
    }
    float mc = sc[0];
    #pragma unroll
    for (int kk = 1; kk < 32; ++kk) mc = fmaxf(mc, sc[kk]);
    const float mn = fmaxf(m, mc);
    const float alpha = __expf(m - mn);
    l *= alpha;
    #pragma unroll
    for (int i = 0; i < 16; ++i) o[i] *= alpha;
    #pragma unroll
    for (int kk = 0; kk < 32; ++kk) {
      const float p = __expf(sc[kk] - mn);
      l += p;
      #pragma unroll
      for (int i = 0; i < 16; ++i) o[i] = fmaf(p, Vsf[kk][dbase + i], o[i]);
    }
    m = mn;
  }
  const float inv = 1.f / fmaxf(l, 1e-30f);
  const int bb = bh >> 4, h = bh & 15;
  const size_t ooff = ((size_t)(bb * SS + qr)) * DM + h * KD + dbase;
  #pragma unroll
  for (int i = 0; i < 16; ++i) obf[ooff + i] = f2s(o[i] * inv);
}

extern "C" void kernel_launch(void* const* d_in, const int* in_sizes, int n_in,
                              void* d_out, int out_size, void* d_ws, size_t ws_size,
                              hipStream_t stream) {
  const float* x      = (const float*)d_in[0];
  const float* w_attn = (const float*)d_in[2];
  const float* b_attn = (const float*)d_in[3];
  const float* w_proj = (const float*)d_in[4];
  const float* b_proj = (const float*)d_in[5];
  float* outf = (float*)d_out;   // fp32: [out0 4M | k 4M | v 4M] elements

  constexpr size_t MB = 1024 * 1024;
  if (ws_size >= 24 * MB) {
    // ---- MFMA-attention path ----
    // ws (shorts): [0,4M) x_bf then o_bf (lifetimes disjoint) |
    //              [4M,7M) w_attn_T | [7M,8M) w_proj_T | [8M,12M) q_bf
    // d_out out0 region (dead until proj): [0,4M) k_bf | [4M,8M) v_bfT
    short* ws0   = (short*)d_ws;
    short* x_bf  = ws0;
    short* o_bf  = ws0;
    short* wat_t = ws0 + (size_t)4 * 1024 * 1024;
    short* wpt_t = ws0 + (size_t)7 * 1024 * 1024;
    short* q_bf  = ws0 + (size_t)8 * 1024 * 1024;
    short* k_bf  = (short*)d_out;
    short* v_bft = k_bf + (size_t)PRES_HALF;

    cast_x_k<<<4096, 256, 0, stream>>>(x, x_bf);
    transpose_k<<<dim3(96, 32), 256, 0, stream>>>(w_attn, 3 * DM, wat_t);
    transpose_k<<<dim3(32, 32), 256, 0, stream>>>(w_proj, DM, wpt_t);

    qkv_mfma_k<<<dim3(24, 32), 256, 0, stream>>>(x_bf, wat_t, b_attn, q_bf, outf,
                                                 k_bf, v_bft);

    attn_mfma5_k<<<dim3(BB * NH * (SS / 64)), 256, 0, stream>>>(q_bf, k_bf, v_bft, o_bf);

    proj_mfma_k<<<dim3(8, 32), 256, 0, stream>>>(o_bf, wpt_t, b_proj, outf);
  } else {
    // ---- legacy fp32-attention fallback ----
    short* x_bf;
    short* q_bf;
    short* wat_t;
    short* wpt_t;
    short* o_bf;
    if (ws_size >= 16 * MB) {
      short* ws = (short*)d_ws;
      x_bf  = (short*)d_out;                 // out0 [0,8MB) dead until proj
      q_bf  = x_bf + OUT_ELEMS;              // out0 [8MB,16MB)
      wat_t = ws;
      wpt_t = wat_t + 3 * DM * DM;
      o_bf  = wat_t + 4 * DM * DM;
    } else {
      x_bf  = (short*)d_out;
      q_bf  = x_bf + OUT_ELEMS;
      wat_t = (short*)d_in[1];
      wpt_t = wat_t + 3 * DM * DM;
      o_bf  = wat_t + 4 * DM * DM;
    }
    cast_x_k<<<4096, 256, 0, stream>>>(x, x_bf);
    transpose_k<<<dim3(96, 32), 256, 0, stream>>>(w_attn, 3 * DM, wat_t);
    transpose_k<<<dim3(32, 32), 256, 0, stream>>>(w_proj, DM, wpt_t);
    qkv_mfma_k<<<dim3(24, 32), 256, 0, stream>>>(x_bf, wat_t, b_attn, q_bf, outf,
                                                 nullptr, nullptr);
    attn_k<<<dim3(BB * NH, SS / 64), 256, 0, stream>>>(q_bf, outf + OUT_ELEMS, o_bf);
    proj_mfma_k<<<dim3(8, 32), 256, 0, stream>>>(o_bf, wpt_t, b_proj, outf);
  }
}